// Round 14
// baseline (681.229 us; speedup 1.0000x reference)
//
#include <hip/hip_runtime.h>
#include <cstdint>
#include <cstddef>

// (B_, S, I, H) = (16, 2048, 256, 512)
#define BB 16
#define SS 2048
#define II 256
#define HH 512
#define MM (BB * SS)        /* 32768 GEMM rows        */
#define NNC 1024            /* out row width (re|im)  */
#define CHUNK 64
#define NCHUNK (SS / CHUNK) /* 32 chunks per batch    */
#define NBLK (BB * NCHUNK)  /* 512 scan blocks        */

using bf16x8 = __attribute__((ext_vector_type(8))) short;
using short8 = __attribute__((ext_vector_type(8))) short;
using f32x4  = __attribute__((ext_vector_type(4))) float;

typedef __attribute__((address_space(3))) uint32_t       lds_u32;
typedef __attribute__((address_space(1))) const uint32_t glb_u32;

__device__ __forceinline__ short f2bf(float f) {
    uint32_t u = __float_as_uint(f);
    u += 0x7fffu + ((u >> 16) & 1u);   // RTNE
    return (short)(u >> 16);
}
__device__ __forceinline__ uint32_t packf16(float a, float b) {
    union { _Float16 h[2]; uint32_t u; } cv;
    cv.h[0] = (_Float16)a; cv.h[1] = (_Float16)b;
    return cv.u;
}
__device__ __forceinline__ float2 unpackf16(uint32_t u) {
    union { uint32_t u; _Float16 h[2]; } cv; cv.u = u;
    return make_float2((float)cv.h[0], (float)cv.h[1]);
}
__device__ __forceinline__ unsigned long long packf2(float a, float b) {
    return (unsigned long long)__float_as_uint(a) |
           ((unsigned long long)__float_as_uint(b) << 32);
}

// ---- fused converts (r12 VERBATIM) + per-launch flag re-zero ----
__global__ __launch_bounds__(256) void cvt_xb(const float4* __restrict__ x,
                                              short8* __restrict__ xb,
                                              const float* __restrict__ Bre,
                                              const float* __restrict__ Bim,
                                              short* __restrict__ Bc,
                                              int* __restrict__ flags) {
    const int bid = blockIdx.x;
    if (bid < 4096) {
        int i = bid * 256 + threadIdx.x;
        float4 v0 = x[2 * i], v1 = x[2 * i + 1];
        short8 o;
        o[0]=f2bf(v0.x); o[1]=f2bf(v0.y); o[2]=f2bf(v0.z); o[3]=f2bf(v0.w);
        o[4]=f2bf(v1.x); o[5]=f2bf(v1.y); o[6]=f2bf(v1.z); o[7]=f2bf(v1.w);
        xb[i] = o;
    } else if (bid < 4224) {
        int idx = (bid - 4096) * 256 + threadIdx.x;  // 32768
        int row = idx >> 5;                           // 0..1023
        int k0  = (idx & 31) << 3;                    // 0..248
        const float* src = ((row & 1) ? Bim : Bre) + (size_t)(row >> 1) * II + k0;
        float4 v0 = *(const float4*)src;
        float4 v1 = *(const float4*)(src + 4);
        short8 o;
        o[0]=f2bf(v0.x); o[1]=f2bf(v0.y); o[2]=f2bf(v0.z); o[3]=f2bf(v0.w);
        o[4]=f2bf(v1.x); o[5]=f2bf(v1.y); o[6]=f2bf(v1.z); o[7]=f2bf(v1.w);
        *(short8*)(Bc + (size_t)row * II + k0) = o;
    } else {
        // re-zero lookback flags EVERY launch (graph-replay safe)
        flags[threadIdx.x * 2]     = 0;
        flags[threadIdx.x * 2 + 1] = 0;
    }
}

// ---- GEMM: r12 VERBATIM (verified; XCD-swizzled, gload_lds both paths) ----
__global__ __launch_bounds__(256, 3) void gemm_pack(const short* __restrict__ Xb,
                                                    const short* __restrict__ Bc,
                                                    uint32_t* __restrict__ Y) {
    __shared__ short Al[2][128 * 32];
    __shared__ short Bl[2][128 * 32];

    const int xcd = blockIdx.x & 7;
    const int k   = blockIdx.x >> 3;          // 0..255
    const int mt  = xcd * 32 + (k >> 3);      // 0..255
    const int nt  = k & 7;
    const int m0 = mt * 128, n0 = nt * 128;
    const int t  = threadIdx.x;
    const int w  = t >> 6, l = t & 63;
    const int fr = l & 15, fg = l >> 4;
    const int wr = w >> 1, wc = w & 1;

    f32x4 acc[4][4] = {};

#pragma unroll
    for (int i = 0; i < 2; ++i) {
        const int ch = i * 256 + t;
        __builtin_amdgcn_global_load_lds(
            (glb_u32*)(Xb + (size_t)(m0 + (ch >> 2)) * II + ((ch & 3) << 3)),
            (lds_u32*)&Al[0][ch * 8], 16, 0, 0);
        __builtin_amdgcn_global_load_lds(
            (glb_u32*)(Bc + (size_t)(n0 + (ch >> 2)) * II + ((ch & 3) << 3)),
            (lds_u32*)&Bl[0][ch * 8], 16, 0, 0);
    }
    __syncthreads();

    for (int ks = 0; ks < 8; ++ks) {         // K = 8 * 32
        const int cur = ks & 1, nxt = cur ^ 1;
        if (ks < 7) {
#pragma unroll
            for (int i = 0; i < 2; ++i) {
                const int ch = i * 256 + t;
                __builtin_amdgcn_global_load_lds(
                    (glb_u32*)(Xb + (size_t)(m0 + (ch >> 2)) * II + (ks + 1) * 32 + ((ch & 3) << 3)),
                    (lds_u32*)&Al[nxt][ch * 8], 16, 0, 0);
                __builtin_amdgcn_global_load_lds(
                    (glb_u32*)(Bc + (size_t)(n0 + (ch >> 2)) * II + (ks + 1) * 32 + ((ch & 3) << 3)),
                    (lds_u32*)&Bl[nxt][ch * 8], 16, 0, 0);
            }
        }
        bf16x8 a[4], b[4];
#pragma unroll
        for (int mi = 0; mi < 4; ++mi)
            a[mi] = *(const bf16x8*)&Al[cur][(wr * 64 + mi * 16 + fr) * 32 + fg * 8];
#pragma unroll
        for (int ni = 0; ni < 4; ++ni)
            b[ni] = *(const bf16x8*)&Bl[cur][(wc * 64 + ni * 16 + fr) * 32 + fg * 8];
#pragma unroll
        for (int mi = 0; mi < 4; ++mi)
#pragma unroll
            for (int ni = 0; ni < 4; ++ni)
                acc[mi][ni] = __builtin_amdgcn_mfma_f32_16x16x32_bf16(
                    a[mi], b[ni], acc[mi][ni], 0, 0, 0);
        __syncthreads();
    }

#pragma unroll
    for (int mi = 0; mi < 4; ++mi)
#pragma unroll
        for (int ni = 0; ni < 4; ++ni) {
            const int row0 = m0 + wr * 64 + mi * 16 + fg * 4;
            const int ncol = n0 + wc * 64 + ni * 16 + fr;
#pragma unroll
            for (int r = 0; r < 4; ++r) {
                float v = acc[mi][ni][r];
                float o = __shfl_xor(v, 1);
                if (!(fr & 1))
                    Y[(size_t)(row0 + r) * HH + (ncol >> 1)] = packf16(v, o);
            }
        }
}

// ---- fused scan: Y read ONCE into registers; E published (r1/r2-verified
// protocol); depth-1 wait on lower-ID blocks (all E's independent); carry
// inline (r12 recurrence); rescan from registers; single out write. ----
__global__ __launch_bounds__(512, 4) void scan_fused(const uint32_t* __restrict__ Y,
                                                     const float* __restrict__ nu,
                                                     const float* __restrict__ th,
                                                     unsigned long long* __restrict__ E,
                                                     int* __restrict__ flags,
                                                     float* __restrict__ out) {
    const int g = blockIdx.x;                 // 512 = 16 b * 32 c
    const int b = g >> 5, c = g & 31;
    const int h = threadIdx.x;                // 512
    const int l = h & 63;
    const float env = __expf(nu[h]);
    const float rad = __expf(-env);
    float s, cs; __sincosf(th[h], &s, &cs);
    const float lre = rad * cs, lim = rad * s;

    // load this chunk's packed Bx into registers (one Y read total)
    const uint32_t* yb = Y + ((size_t)b * SS + (size_t)c * CHUNK) * HH + h;
    uint32_t yv[CHUNK];
#pragma unroll
    for (int t = 0; t < CHUNK; ++t) yv[t] = yb[(size_t)t * HH];

    // chunk-local scan from zero (r12 scan_e body, from registers)
    float hre = 0.f, him = 0.f;
#pragma unroll
    for (int t = 0; t < CHUNK; ++t) {
        const float2 y = unpackf16(yv[t]);
        const float nr = lre * hre - lim * him + y.x;
        him = lre * him + lim * hre + y.y;
        hre = nr;
    }

    // publish E (r1/r2-HW-verified: relaxed agent stores -> barrier -> release flag)
    __hip_atomic_store(&E[(size_t)g * HH + h], packf2(hre, him),
                       __ATOMIC_RELAXED, __HIP_MEMORY_SCOPE_AGENT);
    __syncthreads();
    if (h == 0)
        __hip_atomic_store(&flags[g], 1, __ATOMIC_RELEASE, __HIP_MEMORY_SCOPE_AGENT);

    // inline carry: P = sum_{j<c} lam64^{c-1-j} * E[b,j] (r12 order); each
    // predecessor's E is independent (depth-1 wait, lower blockIdx only).
    const float rL = __expf(-(float)CHUNK * env);
    float sL, cL; __sincosf((float)CHUNK * th[h], &sL, &cL);
    const float l64re = rL * cL, l64im = rL * sL;
    float pre = 0.f, pim = 0.f;
    for (int j = 0; j < c; ++j) {
        int f = 0;
        do {
            if (l == 0)
                f = __hip_atomic_load(&flags[b * NCHUNK + j],
                                      __ATOMIC_ACQUIRE, __HIP_MEMORY_SCOPE_AGENT);
            f = __shfl(f, 0);
            if (!f) __builtin_amdgcn_s_sleep(2);
        } while (!f);
        const unsigned long long v =
            __hip_atomic_load(&E[((size_t)(b * NCHUNK + j)) * HH + h],
                              __ATOMIC_RELAXED, __HIP_MEMORY_SCOPE_AGENT);
        const float eR = __uint_as_float((uint32_t)v);
        const float eI = __uint_as_float((uint32_t)(v >> 32));
        const float nr = l64re * pre - l64im * pim + eR;
        pim = l64re * pim + l64im * pre + eI;
        pre = nr;
    }

    // rescan from registers seeded with P; single out write (r12 body)
    hre = pre; him = pim;
    float* ob = out + ((size_t)b * SS + (size_t)c * CHUNK) * NNC;
#pragma unroll
    for (int t = 0; t < CHUNK; ++t) {
        const float2 y = unpackf16(yv[t]);
        const float nr = lre * hre - lim * him + y.x;
        him = lre * him + lim * hre + y.y;
        hre = nr;
        ob[(size_t)t * NNC + h]      = hre;
        ob[(size_t)t * NNC + HH + h] = him;
    }
}

extern "C" void kernel_launch(void* const* d_in, const int* in_sizes, int n_in,
                              void* d_out, int out_size, void* d_ws, size_t ws_size,
                              hipStream_t stream) {
    const float* x   = (const float*)d_in[0];
    const float* nu  = (const float*)d_in[1];
    const float* th  = (const float*)d_in[2];
    const float* Bre = (const float*)d_in[3];
    const float* Bim = (const float*)d_in[4];
    float* out = (float*)d_out;

    // ws: Xb bf16 16 MiB | Bc bf16 512 KiB | Y u32 64 MiB | E u64 2 MiB | flags 2 KiB
    char* ws = (char*)d_ws;
    short*    Xb = (short*)ws;
    short*    Bc = (short*)(ws + (size_t)MM * II * 2);
    uint32_t* Y  = (uint32_t*)(ws + (size_t)MM * II * 2 + (size_t)NNC * II * 2);
    unsigned long long* E = (unsigned long long*)((char*)Y + (size_t)MM * HH * 4);
    int* flags = (int*)(E + (size_t)NBLK * HH);

    cvt_xb<<<4096 + 128 + 1, 256, 0, stream>>>((const float4*)x, (short8*)Xb,
                                               Bre, Bim, Bc, flags);
    gemm_pack<<<(MM / 128) * (NNC / 128), 256, 0, stream>>>(Xb, Bc, Y);
    scan_fused<<<NBLK, HH, 0, stream>>>(Y, nu, th, E, flags, out);
}

// Round 15
// 159.515 us; speedup vs baseline: 4.2706x; 4.2706x over previous
//
#include <hip/hip_runtime.h>
#include <hip/hip_bf16.h>
#include <cstdint>
#include <cstddef>

// (B_, S, I, H) = (16, 2048, 256, 512)
#define BB 16
#define SS 2048
#define II 256
#define HH 512
#define MM (BB * SS)        /* 32768 GEMM rows        */
#define NNC 1024            /* out row width (re|im)  */
#define CHUNK 64
#define NCHUNK (SS / CHUNK) /* 32 chunks per batch    */

using bf16x8 = __attribute__((ext_vector_type(8))) short;
using short8 = __attribute__((ext_vector_type(8))) short;
using f32x4  = __attribute__((ext_vector_type(4))) float;

typedef __attribute__((address_space(3))) uint32_t       lds_u32;
typedef __attribute__((address_space(1))) const uint32_t glb_u32;

__device__ __forceinline__ short f2bf(float f) {
    uint32_t u = __float_as_uint(f);
    u += 0x7fffu + ((u >> 16) & 1u);   // RTNE
    return (short)(u >> 16);
}
__device__ __forceinline__ uint32_t packf16(float a, float b) {
    union { _Float16 h[2]; uint32_t u; } cv;
    cv.h[0] = (_Float16)a; cv.h[1] = (_Float16)b;
    return cv.u;
}
__device__ __forceinline__ float2 unpackf16(uint32_t u) {
    union { uint32_t u; _Float16 h[2]; } cv; cv.u = u;
    return make_float2((float)cv.h[0], (float)cv.h[1]);
}

// ---- B pack only (x no longer pre-converted): 128 blocks ----
__global__ __launch_bounds__(256) void cvt_b(const float* __restrict__ Bre,
                                             const float* __restrict__ Bim,
                                             short* __restrict__ Bc) {
    int idx = blockIdx.x * 256 + threadIdx.x;    // 32768
    int row = idx >> 5;                           // 0..1023
    int k0  = (idx & 31) << 3;                    // 0..248
    const float* src = ((row & 1) ? Bim : Bre) + (size_t)(row >> 1) * II + k0;
    float4 v0 = *(const float4*)src;
    float4 v1 = *(const float4*)(src + 4);
    short8 o;
    o[0]=f2bf(v0.x); o[1]=f2bf(v0.y); o[2]=f2bf(v0.z); o[3]=f2bf(v0.w);
    o[4]=f2bf(v1.x); o[5]=f2bf(v1.y); o[6]=f2bf(v1.z); o[7]=f2bf(v1.w);
    *(short8*)(Bc + (size_t)row * II + k0) = o;
}

// ---- GEMM: A staged as f32 via global_load_lds (DMA path, 4 issues/k-step);
// f32->bf16 at fragment-read via packed cvt. B path + MFMA + Y r12-VERBATIM. ----
__global__ __launch_bounds__(256, 3) void gemm_pack(const float* __restrict__ X,
                                                    const short* __restrict__ Bc,
                                                    uint32_t* __restrict__ Y) {
    __shared__ float Alf[2][128 * 32];   // 2 x 16 KiB (f32 A-tile)
    __shared__ short Bl[2][128 * 32];    // 2 x 8 KiB

    const int xcd = blockIdx.x & 7;
    const int k   = blockIdx.x >> 3;          // 0..255
    const int mt  = xcd * 32 + (k >> 3);      // 0..255 (bijective; r9-verified)
    const int nt  = k & 7;
    const int m0 = mt * 128, n0 = nt * 128;
    const int t  = threadIdx.x;
    const int w  = t >> 6, l = t & 63;
    const int fr = l & 15, fg = l >> 4;
    const int wr = w >> 1, wc = w & 1;

    f32x4 acc[4][4] = {};

    // ---------------- prologue: stage k-step 0 ----------------
#pragma unroll
    for (int i = 0; i < 4; ++i) {
        const int ch = i * 256 + t;          // 0..1023: row = ch>>3, ko = (ch&7)*4
        __builtin_amdgcn_global_load_lds(
            (glb_u32*)(X + (size_t)(m0 + (ch >> 3)) * II + ((ch & 7) << 2)),
            (lds_u32*)&Alf[0][ch * 4], 16, 0, 0);
    }
#pragma unroll
    for (int i = 0; i < 2; ++i) {
        const int ch = i * 256 + t;
        __builtin_amdgcn_global_load_lds(
            (glb_u32*)(Bc + (size_t)(n0 + (ch >> 2)) * II + ((ch & 3) << 3)),
            (lds_u32*)&Bl[0][ch * 8], 16, 0, 0);
    }
    __syncthreads();

    // ---------------- main loop ----------------
    for (int ks = 0; ks < 8; ++ks) {         // K = 8 * 32
        const int cur = ks & 1, nxt = cur ^ 1;
        if (ks < 7) {
#pragma unroll
            for (int i = 0; i < 4; ++i) {
                const int ch = i * 256 + t;
                __builtin_amdgcn_global_load_lds(
                    (glb_u32*)(X + (size_t)(m0 + (ch >> 3)) * II + (ks + 1) * 32 + ((ch & 7) << 2)),
                    (lds_u32*)&Alf[nxt][ch * 4], 16, 0, 0);
            }
#pragma unroll
            for (int i = 0; i < 2; ++i) {
                const int ch = i * 256 + t;
                __builtin_amdgcn_global_load_lds(
                    (glb_u32*)(Bc + (size_t)(n0 + (ch >> 2)) * II + (ks + 1) * 32 + ((ch & 3) << 3)),
                    (lds_u32*)&Bl[nxt][ch * 8], 16, 0, 0);
            }
        }
        bf16x8 a[4], b[4];
#pragma unroll
        for (int mi = 0; mi < 4; ++mi) {
            const float* ap = &Alf[cur][(wr * 64 + mi * 16 + fr) * 32 + fg * 8];
            const float4 u0 = *(const float4*)ap;
            const float4 u1 = *(const float4*)(ap + 4);
            union { __hip_bfloat162 h[4]; bf16x8 v; } cv;
            cv.h[0] = __float22bfloat162_rn(make_float2(u0.x, u0.y));
            cv.h[1] = __float22bfloat162_rn(make_float2(u0.z, u0.w));
            cv.h[2] = __float22bfloat162_rn(make_float2(u1.x, u1.y));
            cv.h[3] = __float22bfloat162_rn(make_float2(u1.z, u1.w));
            a[mi] = cv.v;
        }
#pragma unroll
        for (int ni = 0; ni < 4; ++ni)
            b[ni] = *(const bf16x8*)&Bl[cur][(wc * 64 + ni * 16 + fr) * 32 + fg * 8];
#pragma unroll
        for (int mi = 0; mi < 4; ++mi)
#pragma unroll
            for (int ni = 0; ni < 4; ++ni)
                acc[mi][ni] = __builtin_amdgcn_mfma_f32_16x16x32_bf16(
                    a[mi], b[ni], acc[mi][ni], 0, 0, 0);
        __syncthreads();
    }

    // ---------------- Y write: r12 VERBATIM ----------------
#pragma unroll
    for (int mi = 0; mi < 4; ++mi)
#pragma unroll
        for (int ni = 0; ni < 4; ++ni) {
            const int row0 = m0 + wr * 64 + mi * 16 + fg * 4;
            const int ncol = n0 + wc * 64 + ni * 16 + fr;
#pragma unroll
            for (int r = 0; r < 4; ++r) {
                float v = acc[mi][ni][r];
                float o = __shfl_xor(v, 1);
                if (!(fr & 1))
                    Y[(size_t)(row0 + r) * HH + (ncol >> 1)] = packf16(v, o);
            }
        }
}

// ---- local chunk scan (h0=0) over packed Y -> chunk-end state E (r12 VERBATIM) ----
__global__ __launch_bounds__(512) void scan_e(const uint32_t* __restrict__ Y,
                                              const float* __restrict__ nu,
                                              const float* __restrict__ th,
                                              float2* __restrict__ E) {
    const int g = blockIdx.x;                 // 512 = 16 b * 32 c
    const int b = g >> 5, c = g & 31;
    const int h = threadIdx.x;
    const float env = __expf(nu[h]);
    const float rad = __expf(-env);
    float s, cs; __sincosf(th[h], &s, &cs);
    const float lre = rad * cs, lim = rad * s;
    const uint32_t* base = Y + ((size_t)b * SS + (size_t)c * CHUNK) * HH + h;
    float hre = 0.f, him = 0.f;
#pragma unroll 8
    for (int t = 0; t < CHUNK; ++t) {
        float2 y = unpackf16(base[(size_t)t * HH]);
        const float nr = lre * hre - lim * him + y.x;
        him = lre * him + lim * hre + y.y;
        hre = nr;
    }
    E[(size_t)g * HH + h] = make_float2(hre, him);
}

// ---- final scan: inline carry from E + r12 scan body (VERBATIM) ----
__global__ __launch_bounds__(512) void scan_final(const uint32_t* __restrict__ Y,
                                                  const float2* __restrict__ E,
                                                  const float* __restrict__ nu,
                                                  const float* __restrict__ th,
                                                  float* __restrict__ out) {
    const int g = blockIdx.x;                 // 512 = 16 b * 32 c
    const int b = g >> 5, c = g & 31;
    const int h = threadIdx.x;
    const float env = __expf(nu[h]);
    const float rad = __expf(-env);
    float s, cs; __sincosf(th[h], &s, &cs);
    const float lre = rad * cs, lim = rad * s;

    const float rL = __expf(-(float)CHUNK * env);
    float sL, cL; __sincosf((float)CHUNK * th[h], &sL, &cL);
    const float l64re = rL * cL, l64im = rL * sL;
    float pre = 0.f, pim = 0.f;
    for (int j = 0; j < c; ++j) {
        const float2 e = E[((size_t)(b * NCHUNK + j)) * HH + h];
        const float nr = l64re * pre - l64im * pim + e.x;
        pim = l64re * pim + l64im * pre + e.y;
        pre = nr;
    }

    float hre = pre, him = pim;
    const uint32_t* yb = Y + ((size_t)b * SS + (size_t)c * CHUNK) * HH + h;
    float* ob = out + ((size_t)b * SS + (size_t)c * CHUNK) * NNC;
#pragma unroll 4
    for (int t = 0; t < CHUNK; ++t) {
        float2 y = unpackf16(yb[(size_t)t * HH]);
        const float nr = lre * hre - lim * him + y.x;
        him = lre * him + lim * hre + y.y;
        hre = nr;
        ob[(size_t)t * NNC + h]      = hre;
        ob[(size_t)t * NNC + HH + h] = him;
    }
}

extern "C" void kernel_launch(void* const* d_in, const int* in_sizes, int n_in,
                              void* d_out, int out_size, void* d_ws, size_t ws_size,
                              hipStream_t stream) {
    const float* x   = (const float*)d_in[0];
    const float* nu  = (const float*)d_in[1];
    const float* th  = (const float*)d_in[2];
    const float* Bre = (const float*)d_in[3];
    const float* Bim = (const float*)d_in[4];
    float* out = (float*)d_out;

    // ws: Bc bf16 512 KiB | Y u32 64 MiB | E 2 MiB
    char* ws = (char*)d_ws;
    short*    Bc = (short*)ws;
    uint32_t* Y  = (uint32_t*)(ws + (size_t)NNC * II * 2);
    float2*   E  = (float2*)((char*)Y + (size_t)MM * HH * 4);

    cvt_b<<<(NNC * II / 8) / 256, 256, 0, stream>>>(Bre, Bim, Bc);
    gemm_pack<<<(MM / 128) * (NNC / 128), 256, 0, stream>>>(x, Bc, Y);
    scan_e<<<BB * NCHUNK, HH, 0, stream>>>(Y, nu, th, E);
    scan_final<<<BB * NCHUNK, HH, 0, stream>>>(Y, E, nu, th, out);
}

// Round 16
// 93.860 us; speedup vs baseline: 7.2579x; 1.6995x over previous
//
#include <hip/hip_runtime.h>
#include <hip/hip_bf16.h>
#include <cstdint>
#include <cstddef>

// (B_, S, I, H) = (16, 2048, 256, 512)
#define BB 16
#define SS 2048
#define II 256
#define HH 512
#define MM (BB * SS)        /* 32768 GEMM rows        */
#define NNC 1024            /* out row width (re|im)  */
#define CHUNK 64
#define NCHUNK (SS / CHUNK) /* 32 chunks per batch    */

using bf16x8 = __attribute__((ext_vector_type(8))) short;
using short8 = __attribute__((ext_vector_type(8))) short;
using f32x4  = __attribute__((ext_vector_type(4))) float;

typedef __attribute__((address_space(3))) uint32_t       lds_u32;
typedef __attribute__((address_space(1))) const uint32_t glb_u32;

__device__ __forceinline__ short f2bf(float f) {
    uint32_t u = __float_as_uint(f);
    u += 0x7fffu + ((u >> 16) & 1u);   // RTNE
    return (short)(u >> 16);
}
__device__ __forceinline__ uint32_t packf16(float a, float b) {
    union { _Float16 h[2]; uint32_t u; } cv;
    cv.h[0] = (_Float16)a; cv.h[1] = (_Float16)b;
    return cv.u;
}
__device__ __forceinline__ float2 unpackf16(uint32_t u) {
    union { uint32_t u; _Float16 h[2]; } cv; cv.u = u;
    return make_float2((float)cv.h[0], (float)cv.h[1]);
}

// ---- B pack only: 128 blocks (r15-verified) ----
__global__ __launch_bounds__(256) void cvt_b(const float* __restrict__ Bre,
                                             const float* __restrict__ Bim,
                                             short* __restrict__ Bc) {
    int idx = blockIdx.x * 256 + threadIdx.x;    // 32768
    int row = idx >> 5;                           // 0..1023
    int k0  = (idx & 31) << 3;                    // 0..248
    const float* src = ((row & 1) ? Bim : Bre) + (size_t)(row >> 1) * II + k0;
    float4 v0 = *(const float4*)src;
    float4 v1 = *(const float4*)(src + 4);
    short8 o;
    o[0]=f2bf(v0.x); o[1]=f2bf(v0.y); o[2]=f2bf(v0.z); o[3]=f2bf(v0.w);
    o[4]=f2bf(v1.x); o[5]=f2bf(v1.y); o[6]=f2bf(v1.z); o[7]=f2bf(v1.w);
    *(short8*)(Bc + (size_t)row * II + k0) = o;
}

// ---- GEMM: A staged f32 via global_load_lds with BOTH-SIDES XOR swizzle
// (linear LDS dest + pre-swizzled global src + swizzled read; rule #21).
// f32->bf16 packed cvt at fragment read (r15-verified numerics).
// B path + MFMA + Y-write r12-VERBATIM. ----
__global__ __launch_bounds__(256, 3) void gemm_pack(const float* __restrict__ X,
                                                    const short* __restrict__ Bc,
                                                    uint32_t* __restrict__ Y) {
    __shared__ float Alf[2][128 * 32];   // 2 x 16 KiB, rows = 8 slots x 16 B
    __shared__ short Bl[2][128 * 32];    // 2 x 8 KiB

    const int xcd = blockIdx.x & 7;
    const int k   = blockIdx.x >> 3;          // 0..255
    const int mt  = xcd * 32 + (k >> 3);      // 0..255 (bijective; r9-verified)
    const int nt  = k & 7;
    const int m0 = mt * 128, n0 = nt * 128;
    const int t  = threadIdx.x;
    const int w  = t >> 6, l = t & 63;
    const int fr = l & 15, fg = l >> 4;
    const int wr = w >> 1, wc = w & 1;

    f32x4 acc[4][4] = {};

    // ---------------- prologue: stage k-step 0 ----------------
#pragma unroll
    for (int i = 0; i < 4; ++i) {
        const int ch = i * 256 + t;          // 0..1023; row = ch>>3, phys slot = ch&7
        const int ar = ch >> 3;
        const int ls = (ch & 7) ^ (ar & 7);  // logical slot held at this phys slot
        __builtin_amdgcn_global_load_lds(
            (glb_u32*)(X + (size_t)(m0 + ar) * II + (ls << 2)),
            (lds_u32*)&Alf[0][ch * 4], 16, 0, 0);
    }
#pragma unroll
    for (int i = 0; i < 2; ++i) {
        const int ch = i * 256 + t;
        __builtin_amdgcn_global_load_lds(
            (glb_u32*)(Bc + (size_t)(n0 + (ch >> 2)) * II + ((ch & 3) << 3)),
            (lds_u32*)&Bl[0][ch * 8], 16, 0, 0);
    }
    __syncthreads();

    // ---------------- main loop ----------------
    for (int ks = 0; ks < 8; ++ks) {         // K = 8 * 32
        const int cur = ks & 1, nxt = cur ^ 1;
        if (ks < 7) {
#pragma unroll
            for (int i = 0; i < 4; ++i) {
                const int ch = i * 256 + t;
                const int ar = ch >> 3;
                const int ls = (ch & 7) ^ (ar & 7);
                __builtin_amdgcn_global_load_lds(
                    (glb_u32*)(X + (size_t)(m0 + ar) * II + (ks + 1) * 32 + (ls << 2)),
                    (lds_u32*)&Alf[nxt][ch * 4], 16, 0, 0);
            }
#pragma unroll
            for (int i = 0; i < 2; ++i) {
                const int ch = i * 256 + t;
                __builtin_amdgcn_global_load_lds(
                    (glb_u32*)(Bc + (size_t)(n0 + (ch >> 2)) * II + (ks + 1) * 32 + ((ch & 3) << 3)),
                    (lds_u32*)&Bl[nxt][ch * 8], 16, 0, 0);
            }
        }
        bf16x8 a[4], b[4];
#pragma unroll
        for (int mi = 0; mi < 4; ++mi) {
            const int arow = wr * 64 + mi * 16 + fr;
            const float* ap = &Alf[cur][arow * 32];
            const int p0 = (fg * 2) ^ (arow & 7);       // phys slot of logical fg*2
            const float4 u0 = *(const float4*)(ap + (p0 << 2));
            const float4 u1 = *(const float4*)(ap + ((p0 ^ 1) << 2));
            union { __hip_bfloat162 h[4]; bf16x8 v; } cv;
            cv.h[0] = __float22bfloat162_rn(make_float2(u0.x, u0.y));
            cv.h[1] = __float22bfloat162_rn(make_float2(u0.z, u0.w));
            cv.h[2] = __float22bfloat162_rn(make_float2(u1.x, u1.y));
            cv.h[3] = __float22bfloat162_rn(make_float2(u1.z, u1.w));
            a[mi] = cv.v;
        }
#pragma unroll
        for (int ni = 0; ni < 4; ++ni)
            b[ni] = *(const bf16x8*)&Bl[cur][(wc * 64 + ni * 16 + fr) * 32 + fg * 8];
#pragma unroll
        for (int mi = 0; mi < 4; ++mi)
#pragma unroll
            for (int ni = 0; ni < 4; ++ni)
                acc[mi][ni] = __builtin_amdgcn_mfma_f32_16x16x32_bf16(
                    a[mi], b[ni], acc[mi][ni], 0, 0, 0);
        __syncthreads();
    }

    // ---------------- Y write: r12 VERBATIM ----------------
#pragma unroll
    for (int mi = 0; mi < 4; ++mi)
#pragma unroll
        for (int ni = 0; ni < 4; ++ni) {
            const int row0 = m0 + wr * 64 + mi * 16 + fg * 4;
            const int ncol = n0 + wc * 64 + ni * 16 + fr;
#pragma unroll
            for (int r = 0; r < 4; ++r) {
                float v = acc[mi][ni][r];
                float o = __shfl_xor(v, 1);
                if (!(fr & 1))
                    Y[(size_t)(row0 + r) * HH + (ncol >> 1)] = packf16(v, o);
            }
        }
}

// ---- local chunk scan (h0=0) over packed Y -> chunk-end state E (r12 VERBATIM) ----
__global__ __launch_bounds__(512) void scan_e(const uint32_t* __restrict__ Y,
                                              const float* __restrict__ nu,
                                              const float* __restrict__ th,
                                              float2* __restrict__ E) {
    const int g = blockIdx.x;                 // 512 = 16 b * 32 c
    const int b = g >> 5, c = g & 31;
    const int h = threadIdx.x;
    const float env = __expf(nu[h]);
    const float rad = __expf(-env);
    float s, cs; __sincosf(th[h], &s, &cs);
    const float lre = rad * cs, lim = rad * s;
    const uint32_t* base = Y + ((size_t)b * SS + (size_t)c * CHUNK) * HH + h;
    float hre = 0.f, him = 0.f;
#pragma unroll 8
    for (int t = 0; t < CHUNK; ++t) {
        float2 y = unpackf16(base[(size_t)t * HH]);
        const float nr = lre * hre - lim * him + y.x;
        him = lre * him + lim * hre + y.y;
        hre = nr;
    }
    E[(size_t)g * HH + h] = make_float2(hre, him);
}

// ---- final scan: inline carry from E + r12 scan body (VERBATIM) ----
__global__ __launch_bounds__(512) void scan_final(const uint32_t* __restrict__ Y,
                                                  const float2* __restrict__ E,
                                                  const float* __restrict__ nu,
                                                  const float* __restrict__ th,
                                                  float* __restrict__ out) {
    const int g = blockIdx.x;                 // 512 = 16 b * 32 c
    const int b = g >> 5, c = g & 31;
    const int h = threadIdx.x;
    const float env = __expf(nu[h]);
    const float rad = __expf(-env);
    float s, cs; __sincosf(th[h], &s, &cs);
    const float lre = rad * cs, lim = rad * s;

    const float rL = __expf(-(float)CHUNK * env);
    float sL, cL; __sincosf((float)CHUNK * th[h], &sL, &cL);
    const float l64re = rL * cL, l64im = rL * sL;
    float pre = 0.f, pim = 0.f;
    for (int j = 0; j < c; ++j) {
        const float2 e = E[((size_t)(b * NCHUNK + j)) * HH + h];
        const float nr = l64re * pre - l64im * pim + e.x;
        pim = l64re * pim + l64im * pre + e.y;
        pre = nr;
    }

    float hre = pre, him = pim;
    const uint32_t* yb = Y + ((size_t)b * SS + (size_t)c * CHUNK) * HH + h;
    float* ob = out + ((size_t)b * SS + (size_t)c * CHUNK) * NNC;
#pragma unroll 4
    for (int t = 0; t < CHUNK; ++t) {
        float2 y = unpackf16(yb[(size_t)t * HH]);
        const float nr = lre * hre - lim * him + y.x;
        him = lre * him + lim * hre + y.y;
        hre = nr;
        ob[(size_t)t * NNC + h]      = hre;
        ob[(size_t)t * NNC + HH + h] = him;
    }
}

extern "C" void kernel_launch(void* const* d_in, const int* in_sizes, int n_in,
                              void* d_out, int out_size, void* d_ws, size_t ws_size,
                              hipStream_t stream) {
    const float* x   = (const float*)d_in[0];
    const float* nu  = (const float*)d_in[1];
    const float* th  = (const float*)d_in[2];
    const float* Bre = (const float*)d_in[3];
    const float* Bim = (const float*)d_in[4];
    float* out = (float*)d_out;

    // ws: Bc bf16 512 KiB | Y u32 64 MiB | E 2 MiB
    char* ws = (char*)d_ws;
    short*    Bc = (short*)ws;
    uint32_t* Y  = (uint32_t*)(ws + (size_t)NNC * II * 2);
    float2*   E  = (float2*)((char*)Y + (size_t)MM * HH * 4);

    cvt_b<<<(NNC * II / 8) / 256, 256, 0, stream>>>(Bre, Bim, Bc);
    gemm_pack<<<(MM / 128) * (NNC / 128), 256, 0, stream>>>(x, Bc, Y);
    scan_e<<<BB * NCHUNK, HH, 0, stream>>>(Y, nu, th, E);
    scan_final<<<BB * NCHUNK, HH, 0, stream>>>(Y, E, nu, th, out);
}

// Round 17
// 90.713 us; speedup vs baseline: 7.5097x; 1.0347x over previous
//
#include <hip/hip_runtime.h>
#include <cstdint>
#include <cstddef>

// (B_, S, I, H) = (16, 2048, 256, 512)
#define BB 16
#define SS 2048
#define II 256
#define HH 512
#define MM (BB * SS)        /* 32768 GEMM rows        */
#define NNC 1024            /* out row width (re|im)  */
#define CHUNK 64
#define NCHUNK (SS / CHUNK) /* 32 chunks per batch    */

using bf16x8 = __attribute__((ext_vector_type(8))) short;
using short8 = __attribute__((ext_vector_type(8))) short;
using f32x4  = __attribute__((ext_vector_type(4))) float;

typedef __attribute__((address_space(3))) uint32_t       lds_u32;
typedef __attribute__((address_space(1))) const uint32_t glb_u32;

__device__ __forceinline__ short f2bf(float f) {
    uint32_t u = __float_as_uint(f);
    u += 0x7fffu + ((u >> 16) & 1u);   // RTNE
    return (short)(u >> 16);
}
__device__ __forceinline__ uint32_t packf16(float a, float b) {
    union { _Float16 h[2]; uint32_t u; } cv;
    cv.h[0] = (_Float16)a; cv.h[1] = (_Float16)b;
    return cv.u;
}
__device__ __forceinline__ float2 unpackf16(uint32_t u) {
    union { uint32_t u; _Float16 h[2]; } cv; cv.u = u;
    return make_float2((float)cv.h[0], (float)cv.h[1]);
}

// ---- fused converts (r4/r10-verified bodies) ----
__global__ __launch_bounds__(256) void cvt_xb(const float4* __restrict__ x,
                                              short8* __restrict__ xb,
                                              const float* __restrict__ Bre,
                                              const float* __restrict__ Bim,
                                              short* __restrict__ Bc) {
    const int bid = blockIdx.x;
    if (bid < 4096) {
        int i = bid * 256 + threadIdx.x;
        float4 v0 = x[2 * i], v1 = x[2 * i + 1];
        short8 o;
        o[0]=f2bf(v0.x); o[1]=f2bf(v0.y); o[2]=f2bf(v0.z); o[3]=f2bf(v0.w);
        o[4]=f2bf(v1.x); o[5]=f2bf(v1.y); o[6]=f2bf(v1.z); o[7]=f2bf(v1.w);
        xb[i] = o;
    } else {
        int idx = (bid - 4096) * 256 + threadIdx.x;  // 32768
        int row = idx >> 5;                           // 0..1023
        int k0  = (idx & 31) << 3;                    // 0..248
        const float* src = ((row & 1) ? Bim : Bre) + (size_t)(row >> 1) * II + k0;
        float4 v0 = *(const float4*)src;
        float4 v1 = *(const float4*)(src + 4);
        short8 o;
        o[0]=f2bf(v0.x); o[1]=f2bf(v0.y); o[2]=f2bf(v0.z); o[3]=f2bf(v0.w);
        o[4]=f2bf(v1.x); o[5]=f2bf(v1.y); o[6]=f2bf(v1.z); o[7]=f2bf(v1.w);
        *(short8*)(Bc + (size_t)row * II + k0) = o;
    }
}

// ---- GEMM: r10 VERBATIM (verified; XCD-swizzled, acc dies at Y-write) ----
__global__ __launch_bounds__(256, 3) void gemm_pack(const short* __restrict__ Xb,
                                                    const short* __restrict__ Bc,
                                                    uint32_t* __restrict__ Y) {
    __shared__ short Al[2][128 * 32];
    __shared__ short Bl[2][128 * 32];

    const int xcd = blockIdx.x & 7;
    const int k   = blockIdx.x >> 3;          // 0..255
    const int mt  = xcd * 32 + (k >> 3);      // 0..255
    const int nt  = k & 7;
    const int m0 = mt * 128, n0 = nt * 128;
    const int t  = threadIdx.x;
    const int w  = t >> 6, l = t & 63;
    const int fr = l & 15, fg = l >> 4;
    const int wr = w >> 1, wc = w & 1;

    f32x4 acc[4][4] = {};

#pragma unroll
    for (int i = 0; i < 2; ++i) {
        const int ch = i * 256 + t;
        __builtin_amdgcn_global_load_lds(
            (glb_u32*)(Xb + (size_t)(m0 + (ch >> 2)) * II + ((ch & 3) << 3)),
            (lds_u32*)&Al[0][ch * 8], 16, 0, 0);
        __builtin_amdgcn_global_load_lds(
            (glb_u32*)(Bc + (size_t)(n0 + (ch >> 2)) * II + ((ch & 3) << 3)),
            (lds_u32*)&Bl[0][ch * 8], 16, 0, 0);
    }
    __syncthreads();

    for (int ks = 0; ks < 8; ++ks) {         // K = 8 * 32
        const int cur = ks & 1, nxt = cur ^ 1;
        if (ks < 7) {
#pragma unroll
            for (int i = 0; i < 2; ++i) {
                const int ch = i * 256 + t;
                __builtin_amdgcn_global_load_lds(
                    (glb_u32*)(Xb + (size_t)(m0 + (ch >> 2)) * II + (ks + 1) * 32 + ((ch & 3) << 3)),
                    (lds_u32*)&Al[nxt][ch * 8], 16, 0, 0);
                __builtin_amdgcn_global_load_lds(
                    (glb_u32*)(Bc + (size_t)(n0 + (ch >> 2)) * II + (ks + 1) * 32 + ((ch & 3) << 3)),
                    (lds_u32*)&Bl[nxt][ch * 8], 16, 0, 0);
            }
        }
        bf16x8 a[4], b[4];
#pragma unroll
        for (int mi = 0; mi < 4; ++mi)
            a[mi] = *(const bf16x8*)&Al[cur][(wr * 64 + mi * 16 + fr) * 32 + fg * 8];
#pragma unroll
        for (int ni = 0; ni < 4; ++ni)
            b[ni] = *(const bf16x8*)&Bl[cur][(wc * 64 + ni * 16 + fr) * 32 + fg * 8];
#pragma unroll
        for (int mi = 0; mi < 4; ++mi)
#pragma unroll
            for (int ni = 0; ni < 4; ++ni)
                acc[mi][ni] = __builtin_amdgcn_mfma_f32_16x16x32_bf16(
                    a[mi], b[ni], acc[mi][ni], 0, 0, 0);
        __syncthreads();
    }

#pragma unroll
    for (int mi = 0; mi < 4; ++mi)
#pragma unroll
        for (int ni = 0; ni < 4; ++ni) {
            const int row0 = m0 + wr * 64 + mi * 16 + fg * 4;
            const int ncol = n0 + wc * 64 + ni * 16 + fr;
#pragma unroll
            for (int r = 0; r < 4; ++r) {
                float v = acc[mi][ni][r];
                float o = __shfl_xor(v, 1);
                if (!(fr & 1))
                    Y[(size_t)(row0 + r) * HH + (ncol >> 1)] = packf16(v, o);
            }
        }
}

// ---- local chunk scan (h0=0) over packed Y -> chunk-end state E (r10 VERBATIM) ----
__global__ __launch_bounds__(512) void scan_e(const uint32_t* __restrict__ Y,
                                              const float* __restrict__ nu,
                                              const float* __restrict__ th,
                                              float2* __restrict__ E) {
    const int g = blockIdx.x;                 // 512 = 16 b * 32 c
    const int b = g >> 5, c = g & 31;
    const int h = threadIdx.x;
    const float env = __expf(nu[h]);
    const float rad = __expf(-env);
    float s, cs; __sincosf(th[h], &s, &cs);
    const float lre = rad * cs, lim = rad * s;
    const uint32_t* base = Y + ((size_t)b * SS + (size_t)c * CHUNK) * HH + h;
    float hre = 0.f, him = 0.f;
#pragma unroll 8
    for (int t = 0; t < CHUNK; ++t) {
        float2 y = unpackf16(base[(size_t)t * HH]);
        const float nr = lre * hre - lim * him + y.x;
        him = lre * him + lim * hre + y.y;
        hre = nr;
    }
    E[(size_t)g * HH + h] = make_float2(hre, him);
}

// ---- final scan: inline carry from E (<=31 MACs, L2-hit) + r10 scan body ----
__global__ __launch_bounds__(512) void scan_final(const uint32_t* __restrict__ Y,
                                                  const float2* __restrict__ E,
                                                  const float* __restrict__ nu,
                                                  const float* __restrict__ th,
                                                  float* __restrict__ out) {
    const int g = blockIdx.x;                 // 512 = 16 b * 32 c
    const int b = g >> 5, c = g & 31;
    const int h = threadIdx.x;
    const float env = __expf(nu[h]);
    const float rad = __expf(-env);
    float s, cs; __sincosf(th[h], &s, &cs);
    const float lre = rad * cs, lim = rad * s;

    // inline carry: P = sum_{j<c} lam64^{c-1-j} * E[b,j]   (r10 recurrence order)
    const float rL = __expf(-(float)CHUNK * env);
    float sL, cL; __sincosf((float)CHUNK * th[h], &sL, &cL);
    const float l64re = rL * cL, l64im = rL * sL;
    float pre = 0.f, pim = 0.f;
    for (int j = 0; j < c; ++j) {
        const float2 e = E[((size_t)(b * NCHUNK + j)) * HH + h];
        const float nr = l64re * pre - l64im * pim + e.x;
        pim = l64re * pim + l64im * pre + e.y;
        pre = nr;
    }

    float hre = pre, him = pim;
    const uint32_t* yb = Y + ((size_t)b * SS + (size_t)c * CHUNK) * HH + h;
    float* ob = out + ((size_t)b * SS + (size_t)c * CHUNK) * NNC;
#pragma unroll 4
    for (int t = 0; t < CHUNK; ++t) {
        float2 y = unpackf16(yb[(size_t)t * HH]);
        const float nr = lre * hre - lim * him + y.x;
        him = lre * him + lim * hre + y.y;
        hre = nr;
        ob[(size_t)t * NNC + h]      = hre;
        ob[(size_t)t * NNC + HH + h] = him;
    }
}

extern "C" void kernel_launch(void* const* d_in, const int* in_sizes, int n_in,
                              void* d_out, int out_size, void* d_ws, size_t ws_size,
                              hipStream_t stream) {
    const float* x   = (const float*)d_in[0];
    const float* nu  = (const float*)d_in[1];
    const float* th  = (const float*)d_in[2];
    const float* Bre = (const float*)d_in[3];
    const float* Bim = (const float*)d_in[4];
    float* out = (float*)d_out;

    // ws: Xb bf16 16 MiB | Bc bf16 512 KiB | Y u32 64 MiB | E 2 MiB
    char* ws = (char*)d_ws;
    short*    Xb = (short*)ws;
    short*    Bc = (short*)(ws + (size_t)MM * II * 2);
    uint32_t* Y  = (uint32_t*)(ws + (size_t)MM * II * 2 + (size_t)NNC * II * 2);
    float2*   E  = (float2*)((char*)Y + (size_t)MM * HH * 4);

    cvt_xb<<<4096 + 128, 256, 0, stream>>>((const float4*)x, (short8*)Xb, Bre, Bim, Bc);
    gemm_pack<<<(MM / 128) * (NNC / 128), 256, 0, stream>>>(Xb, Bc, Y);
    scan_e<<<BB * NCHUNK, HH, 0, stream>>>(Y, nu, th, E);
    scan_final<<<BB * NCHUNK, HH, 0, stream>>>(Y, E, nu, th, out);
}